// Round 4
// baseline (88.896 us; speedup 1.0000x reference)
//
#include <hip/hip_runtime.h>
#include <hip/hip_bf16.h>

// Problem constants
#define B_ 4
#define S_ 4096
#define H_ 1024
#define D_ 64
#define CHUNK 64
#define NCHUNK (S_ / CHUNK)  // 64 chunks per batch

typedef short bf16x8 __attribute__((ext_vector_type(8)));
typedef short bf16x4 __attribute__((ext_vector_type(4)));
typedef float f32x4 __attribute__((ext_vector_type(4)));

// fp32 -> bf16 bits, round-to-nearest-even
__device__ inline unsigned short f2bf(float f) {
    union { float f; unsigned u; } v; v.f = f;
    return (unsigned short)((v.u + 0x7fffu + ((v.u >> 16) & 1u)) >> 16);
}
__device__ inline float bf2f(unsigned short u) {
    union { unsigned u; float f; } v; v.u = (unsigned)u << 16;
    return v.f;
}

__device__ inline bf16x8 cvt8(const float4& a, const float4& b) {
    bf16x8 r;
    r[0] = (short)f2bf(a.x); r[1] = (short)f2bf(a.y);
    r[2] = (short)f2bf(a.z); r[3] = (short)f2bf(a.w);
    r[4] = (short)f2bf(b.x); r[5] = (short)f2bf(b.y);
    r[6] = (short)f2bf(b.z); r[7] = (short)f2bf(b.w);
    return r;
}

// ---------- ROUND-1 PROVEN: prep_w ----------
__global__ void prep_w(const float* __restrict__ Wk, const float* __restrict__ Wv,
                       unsigned short* __restrict__ WkT, unsigned short* __restrict__ WvT) {
    int gid = blockIdx.x * 256 + threadIdx.x;  // gid = d*H + h
    int d = gid >> 10;
    int h = gid & (H_ - 1);
    WkT[gid] = f2bf(Wk[h * D_ + d]);
    WvT[gid] = f2bf(Wv[h * D_ + d]);
}

// ---------- UNDER TEST: kv_moment3 (H-split, 8 waves, LDS reduce) ----------
__global__ __launch_bounds__(512)
void kv_moment3(const float* __restrict__ x, const unsigned short* __restrict__ WkT,
                const unsigned short* __restrict__ WvT, unsigned short* __restrict__ pMb) {
    int blk = blockIdx.x;            // 0..511, 128 blocks per batch
    int b = blk >> 7;
    int s0 = (blk & 127) * 32;
    int tid = threadIdx.x;
    int w = tid >> 6;                // wave 0..7
    int sv = w >> 2;                 // s-subtile 0..1 (16 rows each)
    int hv = w & 3;                  // H-slice 0..3 (256 each)
    int lane = tid & 63;
    int r = lane & 15, kg = lane >> 4;

    __shared__ float pbuf[2][4][16][68];     // 34816 B, reused for K then V
    __shared__ unsigned short Klds[32][68];  // 4352 B
    __shared__ unsigned short Vlds[32][68];  // 4352 B

    f32x4 accK[4] = {}, accV[4] = {};
    const float* xrow = x + ((size_t)b * S_ + s0 + sv * 16 + r) * H_ + hv * 256;

#pragma unroll 2
    for (int it = 0; it < 8; ++it) {
        int kb = it * 32 + kg * 8;
        float4 a0 = *(const float4*)(xrow + kb);
        float4 a1 = *(const float4*)(xrow + kb + 4);
        bf16x8 af = cvt8(a0, a1);
        int kglob = hv * 256 + kb;
#pragma unroll
        for (int nt = 0; nt < 4; ++nt) {
            bf16x8 bk = *(const bf16x8*)(WkT + (nt * 16 + r) * H_ + kglob);
            bf16x8 bv = *(const bf16x8*)(WvT + (nt * 16 + r) * H_ + kglob);
            accK[nt] = __builtin_amdgcn_mfma_f32_16x16x32_bf16(af, bk, accK[nt], 0, 0, 0);
            accV[nt] = __builtin_amdgcn_mfma_f32_16x16x32_bf16(af, bv, accV[nt], 0, 0, 0);
        }
    }

    int row32 = tid >> 4, c4 = tid & 15;  // reduce mapping: 32 rows x 16 col-quads

    // --- K: write partials, reduce across hv, pack bf16 ---
#pragma unroll
    for (int nt = 0; nt < 4; ++nt)
#pragma unroll
        for (int i = 0; i < 4; ++i)
            pbuf[sv][hv][kg * 4 + i][nt * 16 + r] = accK[nt][i];
    __syncthreads();
    {
        f32x4 sk = *(const f32x4*)&pbuf[row32 >> 4][0][row32 & 15][c4 * 4];
#pragma unroll
        for (int hh = 1; hh < 4; ++hh)
            sk += *(const f32x4*)&pbuf[row32 >> 4][hh][row32 & 15][c4 * 4];
        bf16x4 kb4;
#pragma unroll
        for (int j = 0; j < 4; ++j) kb4[j] = (short)f2bf(sk[j]);
        *(bf16x4*)&Klds[row32][c4 * 4] = kb4;
    }
    __syncthreads();

    // --- V: same, reusing pbuf ---
#pragma unroll
    for (int nt = 0; nt < 4; ++nt)
#pragma unroll
        for (int i = 0; i < 4; ++i)
            pbuf[sv][hv][kg * 4 + i][nt * 16 + r] = accV[nt][i];
    __syncthreads();
    {
        f32x4 sv4 = *(const f32x4*)&pbuf[row32 >> 4][0][row32 & 15][c4 * 4];
#pragma unroll
        for (int hh = 1; hh < 4; ++hh)
            sv4 += *(const f32x4*)&pbuf[row32 >> 4][hh][row32 & 15][c4 * 4];
        bf16x4 vb4;
#pragma unroll
        for (int j = 0; j < 4; ++j) vb4[j] = (short)f2bf(sv4[j]);
        *(bf16x4*)&Vlds[row32][c4 * 4] = vb4;
    }
    __syncthreads();

    // Stage 2: Mpart[e][d] = sum_{s<32} K[s][e]*V[s][d], full-K 16x16x32 MFMA.
    int et = w & 3, dh = w >> 2;
    bf16x8 afm;
#pragma unroll
    for (int i = 0; i < 8; ++i)
        afm[i] = (short)Klds[kg * 8 + i][et * 16 + r];
    f32x4 accM[2] = {};
#pragma unroll
    for (int t = 0; t < 2; ++t) {
        int nt = dh * 2 + t;
        bf16x8 bfm;
#pragma unroll
        for (int i = 0; i < 8; ++i)
            bfm[i] = (short)Vlds[kg * 8 + i][nt * 16 + r];
        accM[t] = __builtin_amdgcn_mfma_f32_16x16x32_bf16(afm, bfm, accM[t], 0, 0, 0);
    }
    unsigned short* outp = pMb + (size_t)blk * 4096;
#pragma unroll
    for (int t = 0; t < 2; ++t)
#pragma unroll
        for (int i = 0; i < 4; ++i)
            outp[(et * 16 + kg * 4 + i) * 64 + (dh * 2 + t) * 16 + r] = f2bf(accM[t][i]);
}

// ---------- UNDER TEST: reduce_m3 (128 bf16 partials) ----------
__global__ void reduce_m3(const unsigned short* __restrict__ pMb, float* __restrict__ M) {
    int gid = blockIdx.x * 256 + threadIdx.x;  // 0..16383
    int b = gid >> 12;
    int idx = gid & 4095;
    const unsigned short* p = pMb + (size_t)b * 128 * 4096 + idx;
    float a0 = 0.f, a1 = 0.f, a2 = 0.f, a3 = 0.f;
#pragma unroll 2
    for (int c = 0; c < 128; c += 4) {
        a0 += bf2f(p[(size_t)(c + 0) * 4096]);
        a1 += bf2f(p[(size_t)(c + 1) * 4096]);
        a2 += bf2f(p[(size_t)(c + 2) * 4096]);
        a3 += bf2f(p[(size_t)(c + 3) * 4096]);
    }
    M[gid] = (a0 + a1) + (a2 + a3);
}

// ---------- ROUND-1 PROVEN: make_wp ----------
__global__ void make_wp(const float* __restrict__ Wq, const float* __restrict__ M,
                        unsigned short* __restrict__ WpT) {
    __shared__ float Mcol[64];
    int gid = blockIdx.x * 256 + threadIdx.x;  // b*65536 + d*1024 + h
    int h = gid & (H_ - 1);
    int d = (gid >> 10) & 63;
    int b = gid >> 16;
    if (threadIdx.x < 64) Mcol[threadIdx.x] = M[b * 4096 + threadIdx.x * 64 + d];
    __syncthreads();
    const float4* wq = (const float4*)(Wq + h * 64);
    float acc = 0.f;
#pragma unroll
    for (int e4 = 0; e4 < 16; ++e4) {
        float4 w = wq[e4];
        acc += w.x * Mcol[e4 * 4] + w.y * Mcol[e4 * 4 + 1] +
               w.z * Mcol[e4 * 4 + 2] + w.w * Mcol[e4 * 4 + 3];
    }
    WpT[gid] = f2bf(acc * 0.125f);
}

// ---------- ROUND-1 PROVEN: final_proj (256 blocks, 64 rows, full-H waves) ----------
__global__ __launch_bounds__(256)
void final_proj(const float* __restrict__ x, const unsigned short* __restrict__ WpT,
                float* __restrict__ out) {
    int b = blockIdx.x / NCHUNK;
    int c = blockIdx.x % NCHUNK;
    int s0 = c * CHUNK;
    int wv = threadIdx.x >> 6, lane = threadIdx.x & 63;
    int r = lane & 15, kg = lane >> 4;
    const unsigned short* Wp = WpT + (size_t)b * (D_ * H_);

    f32x4 acc[4] = {};
    const float* xrow = x + ((size_t)b * S_ + s0 + wv * 16 + r) * H_;
    for (int h0 = 0; h0 < H_; h0 += 32) {
        int kb = h0 + kg * 8;
        float4 a0 = *(const float4*)(xrow + kb);
        float4 a1 = *(const float4*)(xrow + kb + 4);
        bf16x8 af = cvt8(a0, a1);
#pragma unroll
        for (int nt = 0; nt < 4; ++nt) {
            bf16x8 bw = *(const bf16x8*)(Wp + (nt * 16 + r) * H_ + kb);
            acc[nt] = __builtin_amdgcn_mfma_f32_16x16x32_bf16(af, bw, acc[nt], 0, 0, 0);
        }
    }
    float* orow = out + ((size_t)b * S_ + s0 + wv * 16) * 64;
#pragma unroll
    for (int nt = 0; nt < 4; ++nt)
#pragma unroll
        for (int i = 0; i < 4; ++i)
            orow[(kg * 4 + i) * 64 + nt * 16 + r] = acc[nt][i];
}

extern "C" void kernel_launch(void* const* d_in, const int* in_sizes, int n_in,
                              void* d_out, int out_size, void* d_ws, size_t ws_size,
                              hipStream_t stream) {
    const float* x  = (const float*)d_in[0];
    const float* Wk = (const float*)d_in[1];
    const float* Wq = (const float*)d_in[2];
    const float* Wv = (const float*)d_in[3];
    float* out = (float*)d_out;

    // Diagnostic guard: if ws is too small, do nothing -> harness sees pure
    // poison (absmax 488) which is a distinct signature from a logic bug.
    if (ws_size < 5046272) return;

    char* ws = (char*)d_ws;
    // layout (total 5,046,272 B == round-1 proven footprint):
    // WkT[128K] | WvT[128K] | WpT[512K] | M[64K fp32] | pMb[4M bf16]
    unsigned short* WkT = (unsigned short*)(ws);
    unsigned short* WvT = (unsigned short*)(ws + 131072);
    unsigned short* WpT = (unsigned short*)(ws + 262144);
    float* M            = (float*)(ws + 786432);
    unsigned short* pMb = (unsigned short*)(ws + 851968);

    prep_w<<<256, 256, 0, stream>>>(Wk, Wv, WkT, WvT);
    kv_moment3<<<512, 512, 0, stream>>>(x, WkT, WvT, pMb);
    reduce_m3<<<64, 256, 0, stream>>>(pMb, M);
    make_wp<<<1024, 256, 0, stream>>>(Wq, M, WpT);
    final_proj<<<256, 256, 0, stream>>>(x, WpT, out);
}